// Round 3
// baseline (254.068 us; speedup 1.0000x reference)
//
#include <hip/hip_runtime.h>
#include <hip/hip_bf16.h>
#include <math.h>

#define NB 64
#define LL 512
#define NF 1024
#define FF 16
#define DD 512

// K1: tokens via f32 discretize (matches XLA/np f32 ops bit-exactly);
// pack 4 tokens/u32; per-b sum & sumsq
__global__ __launch_bounds__(512) void k_tokens(
    const float* __restrict__ x,
    unsigned* __restrict__ tok_pk, int* __restrict__ tsum, int* __restrict__ tsumsq) {
  int b = blockIdx.x, tid = threadIdx.x;
  float xf = x[b * LL + tid];
  float c = (xf + 3.0f) / 6.0f * 10.0f;
  float tf = fminf(fmaxf(floorf(c), 0.0f), 9.0f);
  int t = (int)tf;
  __shared__ unsigned char tc[LL];
  __shared__ int redS[8], redQ[8];
  tc[tid] = (unsigned char)t;
  int s = t, q = t * t;
  #pragma unroll
  for (int o = 32; o > 0; o >>= 1) { s += __shfl_xor(s, o); q += __shfl_xor(q, o); }
  if ((tid & 63) == 0) { redS[tid >> 6] = s; redQ[tid >> 6] = q; }
  __syncthreads();
  if (tid < 128) {
    unsigned u = (unsigned)tc[tid * 4] | ((unsigned)tc[tid * 4 + 1] << 8) |
                 ((unsigned)tc[tid * 4 + 2] << 16) | ((unsigned)tc[tid * 4 + 3] << 24);
    tok_pk[b * 128 + tid] = u;
  }
  if (tid == 0) {
    int S = 0, Q = 0;
    #pragma unroll
    for (int i = 0; i < 8; ++i) { S += redS[i]; Q += redQ[i]; }
    tsum[b] = S; tsumsq[b] = Q;
  }
}

// K2a: interpolated features, transposed layout fiT[l][n] (int8). One block per l:
// interp weight (j,w) is uniform per block.
__global__ __launch_bounds__(256) void k_interp(
    const int* __restrict__ feat, unsigned char* __restrict__ fiT) {
  int l = blockIdx.x, tid = threadIdx.x;
  double u = (double)l * 15.0 / 511.0;
  int j = (int)u; if (j > 14) j = 14;
  double w = u - (double)j;
  #pragma unroll
  for (int k = 0; k < 4; ++k) {
    int n = tid + k * 256;
    int f0 = feat[n * FF + j], f1 = feat[n * FF + j + 1];
    int v = (int)((double)f0 + w * (double)(f1 - f0));  // trunc == astype(int)
    fiT[(size_t)l * NF + n] = (unsigned char)v;
  }
}

// K2b: per-feature sum / sumsq of interpolated row (exact int, same formula as K2a)
__global__ __launch_bounds__(256) void k_fstats(
    const int* __restrict__ feat, int* __restrict__ fsum, int* __restrict__ fsumsq) {
  int n = blockIdx.x, tid = threadIdx.x;
  __shared__ int fr[FF];
  __shared__ int rs[4], rq[4];
  if (tid < FF) fr[tid] = feat[n * FF + tid];
  __syncthreads();
  int s = 0, q = 0;
  #pragma unroll
  for (int k = 0; k < 2; ++k) {
    int l = tid + k * 256;
    double u = (double)l * 15.0 / 511.0;
    int j = (int)u; if (j > 14) j = 14;
    double w = u - (double)j;
    int f0 = fr[j], f1 = fr[j + 1];
    int v = (int)((double)f0 + w * (double)(f1 - f0));
    s += v; q += v * v;
  }
  #pragma unroll
  for (int o = 32; o > 0; o >>= 1) { s += __shfl_xor(s, o); q += __shfl_xor(q, o); }
  if ((tid & 63) == 0) { rs[tid >> 6] = s; rq[tid >> 6] = q; }
  __syncthreads();
  if (tid == 0) {
    int S = 0, Q = 0;
    #pragma unroll
    for (int i = 0; i < 4; ++i) { S += rs[i]; Q += rq[i]; }
    fsum[n] = S; fsumsq[n] = Q;
  }
}

// K3: Levenshtein. Symmetric DP: 17-entry column in registers, stream 512 tokens
// from LDS (packed 4/u32, broadcast reads). One thread per (b,n) pair.
__global__ __launch_bounds__(256) void k_lev(
    const unsigned* __restrict__ tok_pk, const int* __restrict__ feat,
    float* __restrict__ dist) {
  int b = blockIdx.x >> 2;
  int n = ((blockIdx.x & 3) << 8) + threadIdx.x;
  __shared__ unsigned lt[128];
  if (threadIdx.x < 128) lt[threadIdx.x] = tok_pk[b * 128 + threadIdx.x];
  int f[FF];
  const int4* f4 = reinterpret_cast<const int4*>(feat + (size_t)n * FF);
  #pragma unroll
  for (int j = 0; j < 4; ++j) {
    int4 v = f4[j];
    f[j * 4 + 0] = v.x; f[j * 4 + 1] = v.y; f[j * 4 + 2] = v.z; f[j * 4 + 3] = v.w;
  }
  int dp[17];
  #pragma unroll
  for (int j = 0; j <= 16; ++j) dp[j] = j;
  __syncthreads();
  for (int i4 = 0; i4 < 128; ++i4) {
    unsigned u = lt[i4];
    #pragma unroll
    for (int k = 0; k < 4; ++k) {
      int t = (int)((u >> (8 * k)) & 0xffu);
      int p[17];
      #pragma unroll
      for (int j = 1; j <= 16; ++j)
        p[j] = min(dp[j] + 1, dp[j - 1] + (t != f[j - 1]));
      dp[0] = i4 * 4 + k + 1;
      #pragma unroll
      for (int j = 1; j <= 16; ++j)
        dp[j] = min(p[j], dp[j - 1] + 1);
    }
  }
  dist[b * NF + n] = (float)dp[16];
}

// K4: pearson numerator via exact int dot; centering correction via sums.
__global__ __launch_bounds__(256) void k_corr(
    const unsigned* __restrict__ tok_pk, const unsigned char* __restrict__ fiT,
    const int* __restrict__ fsum, const int* __restrict__ fsumsq,
    const int* __restrict__ tsum, const int* __restrict__ tsumsq,
    float* __restrict__ corr) {
  int b = blockIdx.x, tid = threadIdx.x;
  __shared__ unsigned lt[128];
  if (tid < 128) lt[tid] = tok_pk[b * 128 + tid];
  __syncthreads();
  int base = tid * 4;
  int a0 = 0, a1 = 0, a2 = 0, a3 = 0;
  for (int l4 = 0; l4 < 128; ++l4) {
    unsigned tu = lt[l4];
    const unsigned char* fp = fiT + (size_t)l4 * 4 * NF + base;
    #pragma unroll
    for (int k = 0; k < 4; ++k) {
      int t = (int)((tu >> (8 * k)) & 0xffu);
      unsigned qv = *(const unsigned*)(fp + (size_t)k * NF);
      a0 += t * (int)(qv & 0xffu);
      a1 += t * (int)((qv >> 8) & 0xffu);
      a2 += t * (int)((qv >> 16) & 0xffu);
      a3 += t * (int)(qv >> 24);
    }
  }
  float ts = (float)tsum[b];
  float rv = fmaxf((float)tsumsq[b] - ts * ts * (1.0f / 512.0f), 0.0f);
  float rn = sqrtf(rv);
  int acc[4] = {a0, a1, a2, a3};
  #pragma unroll
  for (int r = 0; r < 4; ++r) {
    int n = base + r;
    float fs = (float)fsum[n];
    float fv = fmaxf((float)fsumsq[n] - fs * fs * (1.0f / 512.0f), 0.0f);
    float den = sqrtf(fv) * rn;
    float num = (float)acc[r] - fs * ts * (1.0f / 512.0f);
    corr[b * NF + n] = (den > 0.0f) ? (num / den) : 0.0f;
  }
}

// K5: per-b mean & 1/sqrt(var+eps) of dist (exact in double)
__global__ __launch_bounds__(256) void k_dstats(
    const float* __restrict__ dist, float* __restrict__ dstats) {
  int b = blockIdx.x, tid = threadIdx.x;
  double s = 0.0, q = 0.0;
  #pragma unroll
  for (int k = 0; k < 4; ++k) {
    float v = dist[b * NF + tid + k * 256];
    s += (double)v; q += (double)v * (double)v;
  }
  #pragma unroll
  for (int o = 32; o > 0; o >>= 1) { s += __shfl_xor(s, o); q += __shfl_xor(q, o); }
  __shared__ double rs[4], rq[4];
  if ((tid & 63) == 0) { rs[tid >> 6] = s; rq[tid >> 6] = q; }
  __syncthreads();
  if (tid == 0) {
    double S = 0.0, Q = 0.0;
    #pragma unroll
    for (int i = 0; i < 4; ++i) { S += rs[i]; Q += rq[i]; }
    double m = S * (1.0 / 1024.0);
    double var = Q * (1.0 / 1024.0) - m * m;
    dstats[b * 2] = (float)m;
    dstats[b * 2 + 1] = (float)(1.0 / sqrt(var + 1e-5));
  }
}

// K6: circular 6-tap conv + transpose-write [B,Nf,D]. Write-bound (128 MB).
__global__ __launch_bounds__(256) void k_conv(
    const float* __restrict__ corr, const float* __restrict__ dist,
    const float* __restrict__ dstats, const float* __restrict__ w,
    float* __restrict__ out) {
  int chunk = blockIdx.x;  // 16 chunks of 64 n
  int b = blockIdx.y;
  int tid = threadIdx.x;
  __shared__ float cs[66], ds_[66];
  float m = dstats[b * 2], inv = dstats[b * 2 + 1];
  if (tid < 66) {
    int ng = (chunk * 64 + tid - 1 + NF) & (NF - 1);
    cs[tid] = corr[b * NF + ng];
    ds_[tid] = (dist[b * NF + ng] - m) * inv;
  }
  __syncthreads();
  int d0 = tid * 2;
  float w0[6], w1[6];
  #pragma unroll
  for (int i = 0; i < 6; ++i) {
    w0[i] = w[d0 * 6 + i];
    w1[i] = w[(d0 + 1) * 6 + i];
  }
  const int nb = chunk * 64;
  for (int n = 0; n < 64; ++n) {
    float v0 = cs[n], v1 = cs[n + 1], v2 = cs[n + 2];
    float v3 = ds_[n], v4 = ds_[n + 1], v5 = ds_[n + 2];
    float o0 = w0[0]*v0 + w0[1]*v1 + w0[2]*v2 + w0[3]*v3 + w0[4]*v4 + w0[5]*v5;
    float o1 = w1[0]*v0 + w1[1]*v1 + w1[2]*v2 + w1[3]*v3 + w1[4]*v4 + w1[5]*v5;
    float2* op = (float2*)(out + ((size_t)(b * NF + nb + n)) * DD + d0);
    *op = make_float2(o0, o1);
  }
}

extern "C" void kernel_launch(void* const* d_in, const int* in_sizes, int n_in,
                              void* d_out, int out_size, void* d_ws, size_t ws_size,
                              hipStream_t stream) {
  const float* x = (const float*)d_in[0];                     // [64,512,1] f32
  const int* feat = (const int*)d_in[1];                      // [1024,16] int32
  const float* w = (const float*)d_in[2];                     // [512,2,3] f32
  float* out = (float*)d_out;                                 // [64,1024,512] f32

  char* ws = (char*)d_ws;
  unsigned* tok_pk      = (unsigned*)(ws + 0);            // 64*128*4   = 32768
  unsigned char* fiT    = (unsigned char*)(ws + 32768);   // 512*1024   = 524288
  int* fsum             = (int*)(ws + 557056);            // 4096
  int* fsumsq           = (int*)(ws + 561152);            // 4096
  int* tsum             = (int*)(ws + 565248);            // 256
  int* tsumsq           = (int*)(ws + 565504);            // 256
  float* dist           = (float*)(ws + 565760);          // 262144
  float* corr           = (float*)(ws + 827904);          // 262144
  float* dstats         = (float*)(ws + 1090048);         // 512

  k_tokens<<<NB, 512, 0, stream>>>(x, tok_pk, tsum, tsumsq);
  k_interp<<<LL, 256, 0, stream>>>(feat, fiT);
  k_fstats<<<NF, 256, 0, stream>>>(feat, fsum, fsumsq);
  k_lev<<<256, 256, 0, stream>>>(tok_pk, feat, dist);
  k_corr<<<NB, 256, 0, stream>>>(tok_pk, fiT, fsum, fsumsq, tsum, tsumsq, corr);
  k_dstats<<<NB, 256, 0, stream>>>(dist, dstats);
  k_conv<<<dim3(16, NB), 256, 0, stream>>>(corr, dist, dstats, w, out);
}

// Round 5
// 182.938 us; speedup vs baseline: 1.3888x; 1.3888x over previous
//
#include <hip/hip_runtime.h>
#include <math.h>

#define NB 64
#define LL 512
#define NF 1024
#define FF 16
#define DD 512

// ---- K1 fused prep ----
// blocks 0..63    : tokens for batch b (discretize f32, pack 4/u32, sum & sumsq)
// blocks 64..575  : interp row l -> fiTp layout [l/4][n][l%4] (u8)
// blocks 576..1599: per-feature interp sum/sumsq (exact int, recomputed)
__global__ __launch_bounds__(256) void k_prep(
    const float* __restrict__ x, const int* __restrict__ feat,
    unsigned* __restrict__ tok_pk, int* __restrict__ tsum, int* __restrict__ tsumsq,
    unsigned char* __restrict__ fiTp, int* __restrict__ fsum, int* __restrict__ fsumsq) {
  int tid = threadIdx.x;
  int blk = blockIdx.x;
  if (blk < 64) {
    int b = blk;
    __shared__ unsigned char tc[LL];
    __shared__ int redS[4], redQ[4];
    int s = 0, q = 0;
    #pragma unroll
    for (int k = 0; k < 2; ++k) {
      int l = tid + k * 256;
      float xf = x[b * LL + l];
      float c = (xf + 3.0f) / 6.0f * 10.0f;
      float tf = fminf(fmaxf(floorf(c), 0.0f), 9.0f);
      int t = (int)tf;
      tc[l] = (unsigned char)t;
      s += t; q += t * t;
    }
    #pragma unroll
    for (int o = 32; o > 0; o >>= 1) { s += __shfl_xor(s, o); q += __shfl_xor(q, o); }
    if ((tid & 63) == 0) { redS[tid >> 6] = s; redQ[tid >> 6] = q; }
    __syncthreads();
    if (tid < 128) {
      unsigned u = (unsigned)tc[tid * 4] | ((unsigned)tc[tid * 4 + 1] << 8) |
                   ((unsigned)tc[tid * 4 + 2] << 16) | ((unsigned)tc[tid * 4 + 3] << 24);
      tok_pk[b * 128 + tid] = u;
    }
    if (tid == 0) {
      tsum[b] = redS[0] + redS[1] + redS[2] + redS[3];
      tsumsq[b] = redQ[0] + redQ[1] + redQ[2] + redQ[3];
    }
  } else if (blk < 576) {
    int l = blk - 64;
    double u = (double)l * 15.0 / 511.0;
    int j = (int)u; if (j > 14) j = 14;
    double w = u - (double)j;
    size_t base = (size_t)(l >> 2) * 4096 + (size_t)(l & 3);
    #pragma unroll
    for (int k = 0; k < 4; ++k) {
      int n = tid + k * 256;
      int f0 = feat[n * FF + j], f1 = feat[n * FF + j + 1];
      int v = (int)((double)f0 + w * (double)(f1 - f0));  // trunc == astype(int)
      fiTp[base + (size_t)n * 4] = (unsigned char)v;
    }
  } else {
    int n = blk - 576;
    __shared__ int fr[FF];
    __shared__ int rs[4], rq[4];
    if (tid < FF) fr[tid] = feat[n * FF + tid];
    __syncthreads();
    int s = 0, q = 0;
    #pragma unroll
    for (int k = 0; k < 2; ++k) {
      int l = tid + k * 256;
      double u = (double)l * 15.0 / 511.0;
      int j = (int)u; if (j > 14) j = 14;
      double w = u - (double)j;
      int f0 = fr[j], f1 = fr[j + 1];
      int v = (int)((double)f0 + w * (double)(f1 - f0));
      s += v; q += v * v;
    }
    #pragma unroll
    for (int o = 32; o > 0; o >>= 1) { s += __shfl_xor(s, o); q += __shfl_xor(q, o); }
    if ((tid & 63) == 0) { rs[tid >> 6] = s; rq[tid >> 6] = q; }
    __syncthreads();
    if (tid == 0) {
      fsum[n] = rs[0] + rs[1] + rs[2] + rs[3];
      fsumsq[n] = rq[0] + rq[1] + rq[2] + rq[3];
    }
  }
}

// ---- K2: Myers bit-parallel Levenshtein (m=16 in one word) + fused pearson dot.
// One thread per (b,n). Peq table in LDS [c][tid] (conflict-free, 1 ds_read/token).
// Corr's independent loads+mads fill the Myers dep-chain bubbles.
__global__ __launch_bounds__(256) void k_levc(
    const unsigned* __restrict__ tok_pk, const int* __restrict__ feat,
    const unsigned* __restrict__ fiTp4,
    const int* __restrict__ fsum, const int* __restrict__ fsumsq,
    const int* __restrict__ tsum, const int* __restrict__ tsumsq,
    float* __restrict__ dist, float* __restrict__ corr) {
  int tid = threadIdx.x;
  int b = blockIdx.x >> 2;
  int n = ((blockIdx.x & 3) << 8) + tid;
  __shared__ unsigned lt[128];
  __shared__ unsigned peq[10 * 256];
  if (tid < 128) lt[tid] = tok_pk[b * 128 + tid];
  int f[FF];
  const int4* f4 = reinterpret_cast<const int4*>(feat + (size_t)n * FF);
  #pragma unroll
  for (int j = 0; j < 4; ++j) {
    int4 v = f4[j];
    f[j * 4 + 0] = v.x; f[j * 4 + 1] = v.y; f[j * 4 + 2] = v.z; f[j * 4 + 3] = v.w;
  }
  // Build Peq[c] with static indices only (no scratch), then park in LDS.
  #pragma unroll
  for (int c = 0; c < 10; ++c) {
    unsigned m = 0;
    #pragma unroll
    for (int j = 0; j < 16; ++j) m |= (f[j] == c) ? (1u << j) : 0u;
    peq[c * 256 + tid] = m;
  }
  __syncthreads();
  unsigned VP = 0xFFFFu, VN = 0u;
  int score = 16;
  int acc = 0;
  for (int l4 = 0; l4 < 128; ++l4) {
    unsigned u = lt[l4];                  // block-uniform token quad (broadcast)
    unsigned g = fiTp4[l4 * 1024 + n];    // 4 interp values of column n (coalesced)
    #pragma unroll
    for (int k = 0; k < 4; ++k) {
      unsigned t = (u >> (8 * k)) & 0xffu;
      unsigned Eq = peq[t * 256 + tid];   // 2 lanes/bank -> conflict-free
      unsigned D0 = (((Eq & VP) + VP) ^ VP) | Eq | VN;
      unsigned HP = VN | ~(D0 | VP);
      unsigned HN = D0 & VP;
      score += (int)((HP >> 15) & 1u);
      score -= (int)((HN >> 15) & 1u);
      unsigned X = (HP << 1) | 1u;
      VP = (HN << 1) | ~(D0 | X);
      VN = D0 & X;
      unsigned fi = (g >> (8 * k)) & 0xffu;
      acc += (int)(t * fi);               // mad_u24, off the Myers chain
    }
  }
  dist[b * NF + n] = (float)score;
  float ts = (float)tsum[b];
  float rv = fmaxf((float)tsumsq[b] - ts * ts * (1.0f / 512.0f), 0.0f);
  float rn = sqrtf(rv);
  float fs = (float)fsum[n];
  float fv = fmaxf((float)fsumsq[n] - fs * fs * (1.0f / 512.0f), 0.0f);
  float den = sqrtf(fv) * rn;
  float num = (float)acc - fs * ts * (1.0f / 512.0f);
  corr[b * NF + n] = (den > 0.0f) ? (num / den) : 0.0f;
}

// ---- K3: per-b mean & 1/sqrt(var+eps) of dist (exact in double) ----
__global__ __launch_bounds__(256) void k_dstats(
    const float* __restrict__ dist, float* __restrict__ dstats) {
  int b = blockIdx.x, tid = threadIdx.x;
  double s = 0.0, q = 0.0;
  #pragma unroll
  for (int k = 0; k < 4; ++k) {
    float v = dist[b * NF + tid + k * 256];
    s += (double)v; q += (double)v * (double)v;
  }
  #pragma unroll
  for (int o = 32; o > 0; o >>= 1) { s += __shfl_xor(s, o); q += __shfl_xor(q, o); }
  __shared__ double rs[4], rq[4];
  if ((tid & 63) == 0) { rs[tid >> 6] = s; rq[tid >> 6] = q; }
  __syncthreads();
  if (tid == 0) {
    double S = rs[0] + rs[1] + rs[2] + rs[3];
    double Q = rq[0] + rq[1] + rq[2] + rq[3];
    double m = S * (1.0 / 1024.0);
    double var = Q * (1.0 / 1024.0) - m * m;
    dstats[b * 2] = (float)m;
    dstats[b * 2 + 1] = (float)(1.0 / sqrt(var + 1e-5));
  }
}

// ---- K4: circular 6-tap conv + transpose-write [B,Nf,D]. Write-bound (134 MB). ----
__global__ __launch_bounds__(256) void k_conv(
    const float* __restrict__ corr, const float* __restrict__ dist,
    const float* __restrict__ dstats, const float* __restrict__ w,
    float* __restrict__ out) {
  int chunk = blockIdx.x;  // 16 chunks of 64 n
  int b = blockIdx.y;
  int tid = threadIdx.x;
  __shared__ float cs[66], ds_[66];
  float m = dstats[b * 2], inv = dstats[b * 2 + 1];
  if (tid < 66) {
    int ng = (chunk * 64 + tid - 1 + NF) & (NF - 1);
    cs[tid] = corr[b * NF + ng];
    ds_[tid] = (dist[b * NF + ng] - m) * inv;
  }
  __syncthreads();
  int d0 = tid * 2;
  float w0[6], w1[6];
  #pragma unroll
  for (int i = 0; i < 6; ++i) {
    w0[i] = w[d0 * 6 + i];
    w1[i] = w[(d0 + 1) * 6 + i];
  }
  const int nb = chunk * 64;
  for (int n = 0; n < 64; ++n) {
    float v0 = cs[n], v1 = cs[n + 1], v2 = cs[n + 2];
    float v3 = ds_[n], v4 = ds_[n + 1], v5 = ds_[n + 2];
    float o0 = w0[0]*v0 + w0[1]*v1 + w0[2]*v2 + w0[3]*v3 + w0[4]*v4 + w0[5]*v5;
    float o1 = w1[0]*v0 + w1[1]*v1 + w1[2]*v2 + w1[3]*v3 + w1[4]*v4 + w1[5]*v5;
    float2* op = (float2*)(out + ((size_t)(b * NF + nb + n)) * DD + d0);
    *op = make_float2(o0, o1);
  }
}

extern "C" void kernel_launch(void* const* d_in, const int* in_sizes, int n_in,
                              void* d_out, int out_size, void* d_ws, size_t ws_size,
                              hipStream_t stream) {
  const float* x = (const float*)d_in[0];                     // [64,512,1] f32
  const int* feat = (const int*)d_in[1];                      // [1024,16] int32
  const float* w = (const float*)d_in[2];                     // [512,2,3] f32
  float* out = (float*)d_out;                                 // [64,1024,512] f32

  char* ws = (char*)d_ws;
  unsigned* tok_pk      = (unsigned*)(ws + 0);            // 64*128*4   = 32768
  unsigned char* fiTp   = (unsigned char*)(ws + 32768);   // 512*1024   = 524288
  int* fsum             = (int*)(ws + 557056);            // 4096
  int* fsumsq           = (int*)(ws + 561152);            // 4096
  int* tsum             = (int*)(ws + 565248);            // 256
  int* tsumsq           = (int*)(ws + 565504);            // 256
  float* dist           = (float*)(ws + 565760);          // 262144
  float* corr           = (float*)(ws + 827904);          // 262144
  float* dstats         = (float*)(ws + 1090048);         // 512

  k_prep<<<1600, 256, 0, stream>>>(x, feat, tok_pk, tsum, tsumsq, fiTp, fsum, fsumsq);
  k_levc<<<256, 256, 0, stream>>>(tok_pk, feat, (const unsigned*)fiTp,
                                  fsum, fsumsq, tsum, tsumsq, dist, corr);
  k_dstats<<<NB, 256, 0, stream>>>(dist, dstats);
  k_conv<<<dim3(16, NB), 256, 0, stream>>>(corr, dist, dstats, w, out);
}